// Round 6
// baseline (217.618 us; speedup 1.0000x reference)
//
#include <hip/hip_runtime.h>
#include <stdint.h>

#define NPTS 2048
#define KDIM 4096
#define INVALID_KEY 0xFFFFFFFFFFFFFFFFull

typedef __bf16 bf16x8 __attribute__((ext_vector_type(8)));
typedef float f32x4 __attribute__((ext_vector_type(4)));

__device__ __forceinline__ unsigned short f2bf(float f) {
    unsigned int u = __float_as_uint(f);
    u = (u + 0x7FFFu + ((u >> 16) & 1u)) >> 16;   // RNE
    return (unsigned short)u;
}

__device__ __forceinline__ void gld_lds16(const unsigned short* g, unsigned short* l) {
    __builtin_amdgcn_global_load_lds(
        (const __attribute__((address_space(1))) unsigned int*)g,
        (__attribute__((address_space(3))) unsigned int*)l, 16, 0, 0);
}

// key = (d2_bits << 22) | (min(i,j) << 11) | max(i,j): unique per undirected
// edge -> tie-free total order -> hooking cycles are only mutual 2-cycles.
__device__ __forceinline__ unsigned long long mk_key(float w, int i, int j) {
    unsigned long long a = (i < j) ? i : j;
    unsigned long long b = (i < j) ? j : i;
    return ((unsigned long long)__float_as_uint(w) << 22) | (a << 11) | b;
}

// ---- Kernel 1: fp32->bf16 convert + sqnorm + state init ------------------
__global__ __launch_bounds__(256) void convert_sqnorm_kernel(const float* __restrict__ x,
                                                             unsigned short* __restrict__ xb,
                                                             float* __restrict__ sq,
                                                             int* __restrict__ comp0,
                                                             unsigned long long* __restrict__ best0,
                                                             int* __restrict__ ctl) {
    const int row = blockIdx.x;
    const float* xr = x + (size_t)row * KDIM;
    unsigned short* xbr = xb + (size_t)row * KDIM;
    const int t = threadIdx.x;
    float s = 0.f;
    #pragma unroll
    for (int k = 0; k < 4; ++k) {
        int c = t * 4 + k * 1024;
        float4 v = *(const float4*)(xr + c);
        s += v.x * v.x + v.y * v.y + v.z * v.z + v.w * v.w;
        uint2 u;
        u.x = (unsigned)f2bf(v.x) | ((unsigned)f2bf(v.y) << 16);
        u.y = (unsigned)f2bf(v.z) | ((unsigned)f2bf(v.w) << 16);
        *(uint2*)(xbr + c) = u;
    }
    for (int off = 32; off; off >>= 1) s += __shfl_down(s, off);
    __shared__ float p[4];
    if ((t & 63) == 0) p[t >> 6] = s;
    __syncthreads();
    if (t == 0) {
        sq[row] = p[0] + p[1] + p[2] + p[3];
        comp0[row] = row;
        best0[row] = INVALID_KEY;
        if (row == 0) { ctl[0] = 0; ctl[1] = 0; }
    }
}

// ---- Kernel 2: GEMM D2, 64x64 tile, 4 blocks/CU, 2-phase dbuf ------------
// Measured mechanism (rounds 1/3/5): this 2-phase structure's MfmaUtil is set
// by co-resident-block stall hiding (1 blk/CU=11%, 2=21%). 64x64 tiles give
// 1024 blocks = 4/CU (LDS 32 KB, VGPR ~55). Same chunked XOR-swizzle staging
// (chunk = 16 rows x 32 cols, 1 KB; lane l -> row l>>2, seg (l&3)^((l>>3)&3);
// reader granule 32*m + 8*(q^((m>>1)&3)) -> 2-way bank aliasing, free).
// Wave w computes a 16x64 strip: 8 MFMA + 10 ds_read_b128 per BK=64 step.
__global__ __launch_bounds__(256, 4) void gemm_d2_glds(const unsigned short* __restrict__ xb,
                                                       const float* __restrict__ sq,
                                                       float* __restrict__ D2,
                                                       unsigned long long* __restrict__ best0) {
    __shared__ __align__(16) unsigned short tile[2 * 8192];  // 32 KB, 2 bufs
    const int I0 = blockIdx.y * 64;
    const int J0 = blockIdx.x * 64;
    const int t = threadIdx.x;
    const int lane = t & 63;
    const int w = t >> 6;
    const int m = lane & 15, q = lane >> 4;

    const int rp = lane >> 2;
    const int sg = (lane & 3) ^ ((lane >> 3) & 3);
    // Buffer layout: 16 chunks of 512 elems; chunk (s*8 + c), s = k-half,
    // c<4: A rows c*16; c>=4: B rows (c-4)*16. Wave w stages chunks {2w,2w+1}.
    const unsigned short* gsrc[4]; int ldoff[4];
    #pragma unroll
    for (int s = 0; s < 2; ++s)
        #pragma unroll
        for (int ci = 0; ci < 2; ++ci) {
            int c = w * 2 + ci;                       // chunk 0..7 within k-half
            int rowbase = (c < 4) ? (I0 + c * 16) : (J0 + (c - 4) * 16);
            int idx = s * 2 + ci;
            gsrc[idx] = xb + (size_t)(rowbase + rp) * KDIM + s * 32 + sg * 8;
            ldoff[idx] = (s * 8 + c) * 512;           // wave-uniform LDS chunk base
        }
    const int fro = m * 32 + ((q ^ ((m >> 1) & 3)) * 8);

    f32x4 acc[4] = {};
    unsigned short* buf0 = tile;
    unsigned short* buf1 = tile + 8192;

    auto STAGE = [&](unsigned short* base, int kc) {
        #pragma unroll
        for (int idx = 0; idx < 4; ++idx)
            gld_lds16(gsrc[idx] + kc, base + ldoff[idx]);
    };
    auto COMPUTE = [&](const unsigned short* base) {
        #pragma unroll
        for (int s = 0; s < 2; ++s) {
            bf16x8 af = *(const bf16x8*)(base + (s * 8 + w) * 512 + fro);
            bf16x8 bg[4];
            #pragma unroll
            for (int ct = 0; ct < 4; ++ct)
                bg[ct] = *(const bf16x8*)(base + (s * 8 + 4 + ct) * 512 + fro);
            #pragma unroll
            for (int ct = 0; ct < 4; ++ct)
                acc[ct] = __builtin_amdgcn_mfma_f32_16x16x32_bf16(
                    af, bg[ct], acc[ct], 0, 0, 0);
        }
    };

    STAGE(buf0, 0);
    __syncthreads();
    #pragma unroll 1
    for (int kc = 64; kc < KDIM - 64; kc += 128) {
        STAGE(buf1, kc);
        COMPUTE(buf0);
        __syncthreads();
        STAGE(buf0, kc + 64);
        COMPUTE(buf1);
        __syncthreads();
    }
    STAGE(buf1, KDIM - 64);
    COMPUTE(buf0);
    __syncthreads();
    COMPUTE(buf1);
    __syncthreads();   // all reads done before tile reuse below

    // Epilogue: store D2 + fused per-row min-key (round-0 scan).
    // C/D: col = lane&15, row = q*4+reg  [m89/m91-verified]
    // Wave w owns rows [w*16, w*16+16), cols [0,64) of the tile.
    unsigned long long* s_best = (unsigned long long*)tile;   // reuse post-barrier
    if (t < 64) s_best[t] = INVALID_KEY;
    __syncthreads();
    #pragma unroll
    for (int r = 0; r < 4; ++r) {
        int i = I0 + w * 16 + q * 4 + r;
        unsigned long long kk = INVALID_KEY;
        #pragma unroll
        for (int ct = 0; ct < 4; ++ct) {
            int j = J0 + ct * 16 + m;
            float v = sq[i] + sq[j] - 2.0f * acc[ct][r];
            v = (i == j) ? __builtin_inff() : fmaxf(v, 0.0f);
            D2[(size_t)i * NPTS + j] = v;
            if (i != j) {
                unsigned long long key = mk_key(v, i, j);
                kk = (key < kk) ? key : kk;
            }
        }
        #pragma unroll
        for (int mask = 1; mask < 16; mask <<= 1) {   // butterfly over m
            unsigned long long o = __shfl_xor(kk, mask);
            kk = (o < kk) ? o : kk;
        }
        if (m == 0) atomicMin(&s_best[w * 16 + q * 4 + r], kk);
    }
    __syncthreads();
    if (t < 64) atomicMin(&best0[I0 + t], s_best[t]);
}

// ---- Kernel 3: one Boruvka round, 256 blocks x 512 threads ---------------
// (verified round-5 version; chain ~117 us)
__global__ __launch_bounds__(512) void boruvka_round(const float* __restrict__ D2,
                                                     const unsigned long long* __restrict__ bestP,
                                                     unsigned long long* __restrict__ bestN,
                                                     const int* __restrict__ compP,
                                                     int* __restrict__ compN,
                                                     float* __restrict__ ew,
                                                     int* __restrict__ ctl) {
    if (ctl[1]) return;   // MST complete
    __shared__ int sc[NPTS];                       // 8 KB
    __shared__ unsigned long long compBest[NPTS];  // 16 KB
    __shared__ int par[NPTS];                      // 8 KB, reused as rlist
    __shared__ int s_wsum[8];
    __shared__ int s_nroots;
    const int t = threadIdx.x;
    const int bid = blockIdx.x;
    const int lane = t & 63, w = t >> 6;           // w in 0..7

    if (t == 0) s_nroots = 0;
    #pragma unroll
    for (int e = 0; e < 4; ++e) {
        int v = t * 4 + e;
        sc[v] = compP[v];
        compBest[v] = INVALID_KEY;
    }
    __syncthreads();

    unsigned long long kreg[4]; int oreg[4];
    #pragma unroll
    for (int e = 0; e < 4; ++e) {
        int v = t * 4 + e;
        unsigned long long k = bestP[v];
        kreg[e] = k;
        int a = (int)((k >> 11) & 2047), b = (int)(k & 2047);
        oreg[e] = (a == v) ? b : a;
        if (k != INVALID_KEY && sc[oreg[e]] != sc[v])
            atomicMin(&compBest[sc[v]], k);
    }
    __syncthreads();

    // hook roots (smaller root survives mutual 2-cycle); block 0 records w
    bool isr[4];
    #pragma unroll
    for (int e = 0; e < 4; ++e) {
        int c = t * 4 + e;
        int p = c;
        isr[e] = (sc[c] == c);
        if (isr[e]) {
            unsigned long long k = compBest[c];
            if (k != INVALID_KEY) {
                int a = (int)((k >> 11) & 2047), b = (int)(k & 2047);
                int j = (sc[a] == c) ? b : a;
                int rj = sc[j];
                bool mutual = (compBest[rj] == k);  // keys unique per edge
                if (!(mutual && c < rj)) {
                    p = rj;
                    if (bid == 0)
                        ew[atomicAdd(&ctl[0], 1)] = __uint_as_float((unsigned)(k >> 22));
                }
            }
        }
        par[c] = p;
    }
    // pointer-jump roots until converged (benign races: any read is an ancestor)
    int any = __syncthreads_or(1);   // barrier after par writes
    do {
        int local = 0;
        #pragma unroll
        for (int e = 0; e < 4; ++e) {
            if (isr[e]) {
                int c = t * 4 + e;
                int p = par[c];
                int np = par[p];
                if (np != p) { par[c] = np; local = 1; }
            }
        }
        any = __syncthreads_or(local);
    } while (any);

    int newsc[4]; int rc = 0;
    #pragma unroll
    for (int e = 0; e < 4; ++e) {
        int v = t * 4 + e;
        newsc[e] = par[sc[v]];       // own slot read; par stable
        if (newsc[e] == v) rc++;
    }
    if (rc) atomicAdd(&s_nroots, rc);
    __syncthreads();                 // par reads + nroots adds done
    #pragma unroll
    for (int e = 0; e < 4; ++e) sc[t * 4 + e] = newsc[e];
    __syncthreads();                 // sc visible; par free for reuse
    const int nroots = s_nroots;

    if (bid == 0) {
        #pragma unroll
        for (int e = 0; e < 4; ++e) compN[t * 4 + e] = newsc[e];
        if (t == 0 && nroots == 1) ctl[1] = 1;
    }
    if (nroots == 1) return;

    // rescan list = vertices whose cached edge became internal
    int flags[4], lc = 0;
    #pragma unroll
    for (int e = 0; e < 4; ++e) {
        int v = t * 4 + e;
        flags[e] = (kreg[e] == INVALID_KEY) || (sc[oreg[e]] == sc[v]);
        lc += flags[e];
    }
    int scn = lc;                    // wave inclusive scan
    #pragma unroll
    for (int d = 1; d < 64; d <<= 1) {
        int o = __shfl_up(scn, d);
        if (lane >= d) scn += o;
    }
    if (lane == 63) s_wsum[w] = scn;
    __syncthreads();
    int wbase = 0;
    for (int i = 0; i < w; ++i) wbase += s_wsum[i];
    const int cnt = s_wsum[0] + s_wsum[1] + s_wsum[2] + s_wsum[3] +
                    s_wsum[4] + s_wsum[5] + s_wsum[6] + s_wsum[7];
    int base = wbase + scn - lc;
    int* rlist = par;
    #pragma unroll
    for (int e = 0; e < 4; ++e)
        if (flags[e]) rlist[base++] = t * 4 + e;
    __syncthreads();

    // carry-over still-valid caches: block bid owns vertices [bid*8, bid*8+8)
    if (t < 8) {
        int v = bid * 8 + t;
        unsigned long long k = bestP[v];
        if (k != INVALID_KEY) {
            int a = (int)((k >> 11) & 2047), b = (int)(k & 2047);
            int o = (a == v) ? b : a;
            if (sc[o] != sc[v]) bestN[v] = k;
        }
    }
    // rescan: wave w handles rlist[bid*8 + w]
    int widx = bid * 8 + w;
    if (widx < cnt) {
        int v = rlist[widx];
        int mc = sc[v];
        const float* row = D2 + (size_t)v * NPTS;
        unsigned long long best = INVALID_KEY;
        #pragma unroll
        for (int k = 0; k < 8; ++k) {
            int j0 = k * 256 + lane * 4;
            float4 w4 = *(const float4*)(row + j0);
            int4 c4 = *(const int4*)(sc + j0);
            float wa[4] = {w4.x, w4.y, w4.z, w4.w};
            int ca[4] = {c4.x, c4.y, c4.z, c4.w};
            #pragma unroll
            for (int e = 0; e < 4; ++e) {
                if (ca[e] != mc) {
                    unsigned long long key = mk_key(wa[e], v, j0 + e);
                    best = (key < best) ? key : best;
                }
            }
        }
        for (int off = 32; off; off >>= 1) {
            unsigned long long o = __shfl_down(best, off);
            best = (o < best) ? o : best;
        }
        if (lane == 0) bestN[v] = best;
    }
}

// ---- Kernel 4: sort 2047 weights asc, sqrt, write out --------------------
__global__ __launch_bounds__(1024) void sort_out_kernel(const float* __restrict__ ew,
                                                        float* __restrict__ out) {
    __shared__ float wl[NPTS];
    const int t = threadIdx.x;
    for (int i = t; i < NPTS; i += 1024)
        wl[i] = (i < NPTS - 1) ? ew[i] : __builtin_inff();
    __syncthreads();
    for (int k = 2; k <= NPTS; k <<= 1) {
        for (int j = k >> 1; j > 0; j >>= 1) {
            for (int i = t; i < NPTS; i += 1024) {
                int l = i ^ j;
                if (l > i) {
                    float a = wl[i], b = wl[l];
                    bool up = ((i & k) == 0);
                    if ((a > b) == up) { wl[i] = b; wl[l] = a; }
                }
            }
            __syncthreads();
        }
    }
    for (int i = t; i < NPTS - 1; i += 1024)
        out[i] = sqrtf(fmaxf(wl[i], 0.0f));
}

extern "C" void kernel_launch(void* const* d_in, const int* in_sizes, int n_in,
                              void* d_out, int out_size, void* d_ws, size_t ws_size,
                              hipStream_t stream) {
    const float* x = (const float*)d_in[0];
    float* out = (float*)d_out;
    char* ws = (char*)d_ws;
    unsigned short* xb = (unsigned short*)ws;                          // 16 MB
    float* D2 = (float*)(ws + 16777216);                               // 16 MB
    size_t o = 33554432;
    float* sq = (float*)(ws + o);                  o += 8192;
    unsigned long long* best0 = (unsigned long long*)(ws + o); o += 16384;
    unsigned long long* best1 = (unsigned long long*)(ws + o); o += 16384;
    int* comp0 = (int*)(ws + o);                   o += 8192;
    int* comp1 = (int*)(ws + o);                   o += 8192;
    float* ew = (float*)(ws + o);                  o += 8192;
    int* ctl = (int*)(ws + o);

    hipLaunchKernelGGL(convert_sqnorm_kernel, dim3(NPTS), dim3(256), 0, stream,
                       x, xb, sq, comp0, best0, ctl);
    hipLaunchKernelGGL(gemm_d2_glds, dim3(32, 32), dim3(256), 0, stream,
                       xb, sq, D2, best0);
    for (int r = 0; r < 11; ++r) {
        unsigned long long* bp = (r & 1) ? best1 : best0;
        unsigned long long* bn = (r & 1) ? best0 : best1;
        int* cp = (r & 1) ? comp1 : comp0;
        int* cn = (r & 1) ? comp0 : comp1;
        hipLaunchKernelGGL(boruvka_round, dim3(256), dim3(512), 0, stream,
                           D2, bp, bn, cp, cn, ew, ctl);
    }
    hipLaunchKernelGGL(sort_out_kernel, dim3(1), dim3(1024), 0, stream, ew, out);
}

// Round 7
// 205.102 us; speedup vs baseline: 1.0610x; 1.0610x over previous
//
#include <hip/hip_runtime.h>
#include <stdint.h>

#define NPTS 2048
#define KDIM 4096
#define INVALID_KEY 0xFFFFFFFFFFFFFFFFull

typedef __bf16 bf16x8 __attribute__((ext_vector_type(8)));
typedef float f32x4 __attribute__((ext_vector_type(4)));

__device__ __forceinline__ unsigned short f2bf(float f) {
    unsigned int u = __float_as_uint(f);
    u = (u + 0x7FFFu + ((u >> 16) & 1u)) >> 16;   // RNE
    return (unsigned short)u;
}

__device__ __forceinline__ void gld_lds16(const unsigned short* g, unsigned short* l) {
    __builtin_amdgcn_global_load_lds(
        (const __attribute__((address_space(1))) unsigned int*)g,
        (__attribute__((address_space(3))) unsigned int*)l, 16, 0, 0);
}

// key = (d2_bits << 22) | (min(i,j) << 11) | max(i,j): unique per undirected
// edge -> tie-free total order -> hooking cycles are only mutual 2-cycles.
__device__ __forceinline__ unsigned long long mk_key(float w, int i, int j) {
    unsigned long long a = (i < j) ? i : j;
    unsigned long long b = (i < j) ? j : i;
    return ((unsigned long long)__float_as_uint(w) << 22) | (a << 11) | b;
}

// ---- Kernel 1: fp32->bf16 convert + sqnorm + state init ------------------
__global__ __launch_bounds__(256) void convert_sqnorm_kernel(const float* __restrict__ x,
                                                             unsigned short* __restrict__ xb,
                                                             float* __restrict__ sq,
                                                             int* __restrict__ comp0,
                                                             unsigned long long* __restrict__ best0,
                                                             int* __restrict__ ctl) {
    const int row = blockIdx.x;
    const float* xr = x + (size_t)row * KDIM;
    unsigned short* xbr = xb + (size_t)row * KDIM;
    const int t = threadIdx.x;
    float s = 0.f;
    #pragma unroll
    for (int k = 0; k < 4; ++k) {
        int c = t * 4 + k * 1024;
        float4 v = *(const float4*)(xr + c);
        s += v.x * v.x + v.y * v.y + v.z * v.z + v.w * v.w;
        uint2 u;
        u.x = (unsigned)f2bf(v.x) | ((unsigned)f2bf(v.y) << 16);
        u.y = (unsigned)f2bf(v.z) | ((unsigned)f2bf(v.w) << 16);
        *(uint2*)(xbr + c) = u;
    }
    for (int off = 32; off; off >>= 1) s += __shfl_down(s, off);
    __shared__ float p[4];
    if ((t & 63) == 0) p[t >> 6] = s;
    __syncthreads();
    if (t == 0) {
        sq[row] = p[0] + p[1] + p[2] + p[3];
        comp0[row] = row;
        best0[row] = INVALID_KEY;
        if (row == 0) { ctl[0] = 0; ctl[1] = 0; }
    }
}

// ---- Kernel 2: GEMM D2, 64x128, BK=64, 2-phase dbuf + XCD swizzle --------
// Verified round-1 body. Tile-size ladder measured: 64x64@4blk/CU = 69 us
// (MfmaUtil 20, co-residency saturates at 2), 64x128@2blk/CU = 57-66 us,
// 272-tile triangular@1blk/CU = 62 us (MfmaUtil 11). Added: T1 XCD swizzle
// (swz = (bid%8)*64 + bid/8, bijective since 512%8==0): each XCD gets 64
// consecutive tiles = 4 A-panels (2 MB, L2-resident) instead of ~32 panels
// round-robined -> better L2 hit rate -> shorter stage latency.
__global__ __launch_bounds__(256, 2) void gemm_d2_glds(const unsigned short* __restrict__ xb,
                                                       const float* __restrict__ sq,
                                                       float* __restrict__ D2,
                                                       unsigned long long* __restrict__ best0) {
    __shared__ __align__(16) unsigned short tile[2 * 12288];  // 48 KB, 2 bufs
    const int swz = (blockIdx.x & 7) * 64 + (blockIdx.x >> 3);  // XCD-chunked
    const int I0 = (swz >> 4) * 64;    // by = swz/16
    const int J0 = (swz & 15) * 128;   // bx = swz%16
    const int t = threadIdx.x;
    const int lane = t & 63;
    const int w = t >> 6;
    const int m = lane & 15, q = lane >> 4;

    // Staging lane l holds (row=l>>2, seg=(l&3)^((l>>3)&3)) within a chunk;
    // reader granule (m, q) sits at 32*m + 8*(q^((m>>1)&3)) elems -> 2-way
    // bank aliasing only (free). Swizzle applied on BOTH sides (rule #21).
    const int rp = lane >> 2;
    const int sg = (lane & 3) ^ ((lane >> 3) & 3);
    const unsigned short* gsrc[6]; int ldoff[6];
    #pragma unroll
    for (int s = 0; s < 2; ++s)
        #pragma unroll
        for (int ci = 0; ci < 3; ++ci) {
            int c = w * 3 + ci;                       // chunk 0..11 within sub-tile
            int rowbase = (c < 4) ? (I0 + c * 16) : (J0 + (c - 4) * 16);
            int idx = s * 3 + ci;
            gsrc[idx] = xb + (size_t)(rowbase + rp) * KDIM + s * 32 + sg * 8;
            ldoff[idx] = (s * 12 + c) * 512;          // wave-uniform LDS chunk base
        }
    const int fro = m * 32 + ((q ^ ((m >> 1) & 3)) * 8);

    f32x4 acc[4][2] = {};
    unsigned short* buf0 = tile;
    unsigned short* buf1 = tile + 12288;

    auto STAGE = [&](unsigned short* base, int kc) {
        #pragma unroll
        for (int idx = 0; idx < 6; ++idx)
            gld_lds16(gsrc[idx] + kc, base + ldoff[idx]);
    };
    auto COMPUTE = [&](const unsigned short* base) {
        #pragma unroll
        for (int s = 0; s < 2; ++s) {
            bf16x8 af[4], bg[2];
            #pragma unroll
            for (int rt = 0; rt < 4; ++rt)
                af[rt] = *(const bf16x8*)(base + (s * 12 + rt) * 512 + fro);
            #pragma unroll
            for (int ct = 0; ct < 2; ++ct)
                bg[ct] = *(const bf16x8*)(base + (s * 12 + 4 + w * 2 + ct) * 512 + fro);
            #pragma unroll
            for (int rt = 0; rt < 4; ++rt)
                #pragma unroll
                for (int ct = 0; ct < 2; ++ct)
                    acc[rt][ct] = __builtin_amdgcn_mfma_f32_16x16x32_bf16(
                        af[rt], bg[ct], acc[rt][ct], 0, 0, 0);
        }
    };

    STAGE(buf0, 0);
    __syncthreads();
    #pragma unroll 1
    for (int kc = 64; kc < KDIM - 64; kc += 128) {
        STAGE(buf1, kc);
        COMPUTE(buf0);
        __syncthreads();
        STAGE(buf0, kc + 64);
        COMPUTE(buf1);
        __syncthreads();
    }
    STAGE(buf1, KDIM - 64);
    COMPUTE(buf0);
    __syncthreads();
    COMPUTE(buf1);
    __syncthreads();   // all reads done before tile reuse below

    // Epilogue: store D2 + fused per-row min-key (round-0 scan).
    // C/D: col = lane&15, row = q*4+reg  [m89/m91-verified]
    unsigned long long* s_best = (unsigned long long*)tile;   // reuse post-barrier
    if (t < 64) s_best[t] = INVALID_KEY;
    __syncthreads();
    #pragma unroll
    for (int rt = 0; rt < 4; ++rt) {
        #pragma unroll
        for (int r = 0; r < 4; ++r) {
            int i = I0 + rt * 16 + q * 4 + r;
            unsigned long long kk = INVALID_KEY;
            #pragma unroll
            for (int ct = 0; ct < 2; ++ct) {
                int j = J0 + w * 32 + ct * 16 + m;
                float v = sq[i] + sq[j] - 2.0f * acc[rt][ct][r];
                v = (i == j) ? __builtin_inff() : fmaxf(v, 0.0f);
                D2[(size_t)i * NPTS + j] = v;
                if (i != j) {
                    unsigned long long key = mk_key(v, i, j);
                    kk = (key < kk) ? key : kk;
                }
            }
            #pragma unroll
            for (int mask = 1; mask < 16; mask <<= 1) {   // butterfly over m
                unsigned long long o = __shfl_xor(kk, mask);
                kk = (o < kk) ? o : kk;
            }
            if (m == 0) atomicMin(&s_best[rt * 16 + q * 4 + r], kk);
        }
    }
    __syncthreads();
    if (t < 64) atomicMin(&best0[I0 + t], s_best[t]);
}

// ---- Kernel 3: one Boruvka round, 256 blocks x 512 threads ---------------
// (verified round-5 version; chain ~117 us)
__global__ __launch_bounds__(512) void boruvka_round(const float* __restrict__ D2,
                                                     const unsigned long long* __restrict__ bestP,
                                                     unsigned long long* __restrict__ bestN,
                                                     const int* __restrict__ compP,
                                                     int* __restrict__ compN,
                                                     float* __restrict__ ew,
                                                     int* __restrict__ ctl) {
    if (ctl[1]) return;   // MST complete
    __shared__ int sc[NPTS];                       // 8 KB
    __shared__ unsigned long long compBest[NPTS];  // 16 KB
    __shared__ int par[NPTS];                      // 8 KB, reused as rlist
    __shared__ int s_wsum[8];
    __shared__ int s_nroots;
    const int t = threadIdx.x;
    const int bid = blockIdx.x;
    const int lane = t & 63, w = t >> 6;           // w in 0..7

    if (t == 0) s_nroots = 0;
    #pragma unroll
    for (int e = 0; e < 4; ++e) {
        int v = t * 4 + e;
        sc[v] = compP[v];
        compBest[v] = INVALID_KEY;
    }
    __syncthreads();

    unsigned long long kreg[4]; int oreg[4];
    #pragma unroll
    for (int e = 0; e < 4; ++e) {
        int v = t * 4 + e;
        unsigned long long k = bestP[v];
        kreg[e] = k;
        int a = (int)((k >> 11) & 2047), b = (int)(k & 2047);
        oreg[e] = (a == v) ? b : a;
        if (k != INVALID_KEY && sc[oreg[e]] != sc[v])
            atomicMin(&compBest[sc[v]], k);
    }
    __syncthreads();

    // hook roots (smaller root survives mutual 2-cycle); block 0 records w
    bool isr[4];
    #pragma unroll
    for (int e = 0; e < 4; ++e) {
        int c = t * 4 + e;
        int p = c;
        isr[e] = (sc[c] == c);
        if (isr[e]) {
            unsigned long long k = compBest[c];
            if (k != INVALID_KEY) {
                int a = (int)((k >> 11) & 2047), b = (int)(k & 2047);
                int j = (sc[a] == c) ? b : a;
                int rj = sc[j];
                bool mutual = (compBest[rj] == k);  // keys unique per edge
                if (!(mutual && c < rj)) {
                    p = rj;
                    if (bid == 0)
                        ew[atomicAdd(&ctl[0], 1)] = __uint_as_float((unsigned)(k >> 22));
                }
            }
        }
        par[c] = p;
    }
    // pointer-jump roots until converged (benign races: any read is an ancestor)
    int any = __syncthreads_or(1);   // barrier after par writes
    do {
        int local = 0;
        #pragma unroll
        for (int e = 0; e < 4; ++e) {
            if (isr[e]) {
                int c = t * 4 + e;
                int p = par[c];
                int np = par[p];
                if (np != p) { par[c] = np; local = 1; }
            }
        }
        any = __syncthreads_or(local);
    } while (any);

    int newsc[4]; int rc = 0;
    #pragma unroll
    for (int e = 0; e < 4; ++e) {
        int v = t * 4 + e;
        newsc[e] = par[sc[v]];       // own slot read; par stable
        if (newsc[e] == v) rc++;
    }
    if (rc) atomicAdd(&s_nroots, rc);
    __syncthreads();                 // par reads + nroots adds done
    #pragma unroll
    for (int e = 0; e < 4; ++e) sc[t * 4 + e] = newsc[e];
    __syncthreads();                 // sc visible; par free for reuse
    const int nroots = s_nroots;

    if (bid == 0) {
        #pragma unroll
        for (int e = 0; e < 4; ++e) compN[t * 4 + e] = newsc[e];
        if (t == 0 && nroots == 1) ctl[1] = 1;
    }
    if (nroots == 1) return;

    // rescan list = vertices whose cached edge became internal
    int flags[4], lc = 0;
    #pragma unroll
    for (int e = 0; e < 4; ++e) {
        int v = t * 4 + e;
        flags[e] = (kreg[e] == INVALID_KEY) || (sc[oreg[e]] == sc[v]);
        lc += flags[e];
    }
    int scn = lc;                    // wave inclusive scan
    #pragma unroll
    for (int d = 1; d < 64; d <<= 1) {
        int o = __shfl_up(scn, d);
        if (lane >= d) scn += o;
    }
    if (lane == 63) s_wsum[w] = scn;
    __syncthreads();
    int wbase = 0;
    for (int i = 0; i < w; ++i) wbase += s_wsum[i];
    const int cnt = s_wsum[0] + s_wsum[1] + s_wsum[2] + s_wsum[3] +
                    s_wsum[4] + s_wsum[5] + s_wsum[6] + s_wsum[7];
    int base = wbase + scn - lc;
    int* rlist = par;
    #pragma unroll
    for (int e = 0; e < 4; ++e)
        if (flags[e]) rlist[base++] = t * 4 + e;
    __syncthreads();

    // carry-over still-valid caches: block bid owns vertices [bid*8, bid*8+8)
    if (t < 8) {
        int v = bid * 8 + t;
        unsigned long long k = bestP[v];
        if (k != INVALID_KEY) {
            int a = (int)((k >> 11) & 2047), b = (int)(k & 2047);
            int o = (a == v) ? b : a;
            if (sc[o] != sc[v]) bestN[v] = k;
        }
    }
    // rescan: wave w handles rlist[bid*8 + w]
    int widx = bid * 8 + w;
    if (widx < cnt) {
        int v = rlist[widx];
        int mc = sc[v];
        const float* row = D2 + (size_t)v * NPTS;
        unsigned long long best = INVALID_KEY;
        #pragma unroll
        for (int k = 0; k < 8; ++k) {
            int j0 = k * 256 + lane * 4;
            float4 w4 = *(const float4*)(row + j0);
            int4 c4 = *(const int4*)(sc + j0);
            float wa[4] = {w4.x, w4.y, w4.z, w4.w};
            int ca[4] = {c4.x, c4.y, c4.z, c4.w};
            #pragma unroll
            for (int e = 0; e < 4; ++e) {
                if (ca[e] != mc) {
                    unsigned long long key = mk_key(wa[e], v, j0 + e);
                    best = (key < best) ? key : best;
                }
            }
        }
        for (int off = 32; off; off >>= 1) {
            unsigned long long o = __shfl_down(best, off);
            best = (o < best) ? o : best;
        }
        if (lane == 0) bestN[v] = best;
    }
}

// ---- Kernel 4: sort 2047 weights asc, sqrt, write out --------------------
__global__ __launch_bounds__(1024) void sort_out_kernel(const float* __restrict__ ew,
                                                        float* __restrict__ out) {
    __shared__ float wl[NPTS];
    const int t = threadIdx.x;
    for (int i = t; i < NPTS; i += 1024)
        wl[i] = (i < NPTS - 1) ? ew[i] : __builtin_inff();
    __syncthreads();
    for (int k = 2; k <= NPTS; k <<= 1) {
        for (int j = k >> 1; j > 0; j >>= 1) {
            for (int i = t; i < NPTS; i += 1024) {
                int l = i ^ j;
                if (l > i) {
                    float a = wl[i], b = wl[l];
                    bool up = ((i & k) == 0);
                    if ((a > b) == up) { wl[i] = b; wl[l] = a; }
                }
            }
            __syncthreads();
        }
    }
    for (int i = t; i < NPTS - 1; i += 1024)
        out[i] = sqrtf(fmaxf(wl[i], 0.0f));
}

extern "C" void kernel_launch(void* const* d_in, const int* in_sizes, int n_in,
                              void* d_out, int out_size, void* d_ws, size_t ws_size,
                              hipStream_t stream) {
    const float* x = (const float*)d_in[0];
    float* out = (float*)d_out;
    char* ws = (char*)d_ws;
    unsigned short* xb = (unsigned short*)ws;                          // 16 MB
    float* D2 = (float*)(ws + 16777216);                               // 16 MB
    size_t o = 33554432;
    float* sq = (float*)(ws + o);                  o += 8192;
    unsigned long long* best0 = (unsigned long long*)(ws + o); o += 16384;
    unsigned long long* best1 = (unsigned long long*)(ws + o); o += 16384;
    int* comp0 = (int*)(ws + o);                   o += 8192;
    int* comp1 = (int*)(ws + o);                   o += 8192;
    float* ew = (float*)(ws + o);                  o += 8192;
    int* ctl = (int*)(ws + o);

    hipLaunchKernelGGL(convert_sqnorm_kernel, dim3(NPTS), dim3(256), 0, stream,
                       x, xb, sq, comp0, best0, ctl);
    hipLaunchKernelGGL(gemm_d2_glds, dim3(512), dim3(256), 0, stream,
                       xb, sq, D2, best0);
    for (int r = 0; r < 11; ++r) {
        unsigned long long* bp = (r & 1) ? best1 : best0;
        unsigned long long* bn = (r & 1) ? best0 : best1;
        int* cp = (r & 1) ? comp1 : comp0;
        int* cn = (r & 1) ? comp0 : comp1;
        hipLaunchKernelGGL(boruvka_round, dim3(256), dim3(512), 0, stream,
                           D2, bp, bn, cp, cn, ew, ctl);
    }
    hipLaunchKernelGGL(sort_out_kernel, dim3(1), dim3(1024), 0, stream, ew, out);
}

// Round 8
// 200.340 us; speedup vs baseline: 1.0862x; 1.0238x over previous
//
#include <hip/hip_runtime.h>
#include <stdint.h>

#define NPTS 2048
#define KDIM 4096
#define INVALID_KEY 0xFFFFFFFFFFFFFFFFull

typedef __bf16 bf16x8 __attribute__((ext_vector_type(8)));
typedef float f32x4 __attribute__((ext_vector_type(4)));

__device__ __forceinline__ unsigned short f2bf(float f) {
    unsigned int u = __float_as_uint(f);
    u = (u + 0x7FFFu + ((u >> 16) & 1u)) >> 16;   // RNE
    return (unsigned short)u;
}

__device__ __forceinline__ void gld_lds16(const unsigned short* g, unsigned short* l) {
    __builtin_amdgcn_global_load_lds(
        (const __attribute__((address_space(1))) unsigned int*)g,
        (__attribute__((address_space(3))) unsigned int*)l, 16, 0, 0);
}

// key = (d2_bits << 22) | (min(i,j) << 11) | max(i,j): unique per undirected
// edge -> tie-free total order -> hooking cycles are only mutual 2-cycles.
__device__ __forceinline__ unsigned long long mk_key(float w, int i, int j) {
    unsigned long long a = (i < j) ? i : j;
    unsigned long long b = (i < j) ? j : i;
    return ((unsigned long long)__float_as_uint(w) << 22) | (a << 11) | b;
}

// ---- Kernel 1: fp32->bf16 convert + sqnorm + state init ------------------
__global__ __launch_bounds__(256) void convert_sqnorm_kernel(const float* __restrict__ x,
                                                             unsigned short* __restrict__ xb,
                                                             float* __restrict__ sq,
                                                             int* __restrict__ comp0,
                                                             unsigned long long* __restrict__ best0,
                                                             int* __restrict__ ctl) {
    const int row = blockIdx.x;
    const float* xr = x + (size_t)row * KDIM;
    unsigned short* xbr = xb + (size_t)row * KDIM;
    const int t = threadIdx.x;
    float s = 0.f;
    #pragma unroll
    for (int k = 0; k < 4; ++k) {
        int c = t * 4 + k * 1024;
        float4 v = *(const float4*)(xr + c);
        s += v.x * v.x + v.y * v.y + v.z * v.z + v.w * v.w;
        uint2 u;
        u.x = (unsigned)f2bf(v.x) | ((unsigned)f2bf(v.y) << 16);
        u.y = (unsigned)f2bf(v.z) | ((unsigned)f2bf(v.w) << 16);
        *(uint2*)(xbr + c) = u;
    }
    for (int off = 32; off; off >>= 1) s += __shfl_down(s, off);
    __shared__ float p[4];
    if ((t & 63) == 0) p[t >> 6] = s;
    __syncthreads();
    if (t == 0) {
        sq[row] = p[0] + p[1] + p[2] + p[3];
        comp0[row] = row;
        best0[row] = INVALID_KEY;
        if (row == 0) { ctl[0] = 0; ctl[1] = 0; }
    }
}

// ---- Kernel 2: GEMM D2, 64x128, BK=64, 2-phase dbuf + XCD swizzle --------
// (frozen round-7 version: 54 us, MfmaUtil ~24%. Tile ladder measured:
// 64x64@4blk/CU=69us, 64x128@2blk/CU=54-66us, triangular@1blk/CU=62us.)
__global__ __launch_bounds__(256, 2) void gemm_d2_glds(const unsigned short* __restrict__ xb,
                                                       const float* __restrict__ sq,
                                                       float* __restrict__ D2,
                                                       unsigned long long* __restrict__ best0) {
    __shared__ __align__(16) unsigned short tile[2 * 12288];  // 48 KB, 2 bufs
    const int swz = (blockIdx.x & 7) * 64 + (blockIdx.x >> 3);  // XCD-chunked
    const int I0 = (swz >> 4) * 64;    // by = swz/16
    const int J0 = (swz & 15) * 128;   // bx = swz%16
    const int t = threadIdx.x;
    const int lane = t & 63;
    const int w = t >> 6;
    const int m = lane & 15, q = lane >> 4;

    // Staging lane l holds (row=l>>2, seg=(l&3)^((l>>3)&3)) within a chunk;
    // reader granule (m, q) sits at 32*m + 8*(q^((m>>1)&3)) elems -> 2-way
    // bank aliasing only (free). Swizzle applied on BOTH sides (rule #21).
    const int rp = lane >> 2;
    const int sg = (lane & 3) ^ ((lane >> 3) & 3);
    const unsigned short* gsrc[6]; int ldoff[6];
    #pragma unroll
    for (int s = 0; s < 2; ++s)
        #pragma unroll
        for (int ci = 0; ci < 3; ++ci) {
            int c = w * 3 + ci;                       // chunk 0..11 within sub-tile
            int rowbase = (c < 4) ? (I0 + c * 16) : (J0 + (c - 4) * 16);
            int idx = s * 3 + ci;
            gsrc[idx] = xb + (size_t)(rowbase + rp) * KDIM + s * 32 + sg * 8;
            ldoff[idx] = (s * 12 + c) * 512;          // wave-uniform LDS chunk base
        }
    const int fro = m * 32 + ((q ^ ((m >> 1) & 3)) * 8);

    f32x4 acc[4][2] = {};
    unsigned short* buf0 = tile;
    unsigned short* buf1 = tile + 12288;

    auto STAGE = [&](unsigned short* base, int kc) {
        #pragma unroll
        for (int idx = 0; idx < 6; ++idx)
            gld_lds16(gsrc[idx] + kc, base + ldoff[idx]);
    };
    auto COMPUTE = [&](const unsigned short* base) {
        #pragma unroll
        for (int s = 0; s < 2; ++s) {
            bf16x8 af[4], bg[2];
            #pragma unroll
            for (int rt = 0; rt < 4; ++rt)
                af[rt] = *(const bf16x8*)(base + (s * 12 + rt) * 512 + fro);
            #pragma unroll
            for (int ct = 0; ct < 2; ++ct)
                bg[ct] = *(const bf16x8*)(base + (s * 12 + 4 + w * 2 + ct) * 512 + fro);
            #pragma unroll
            for (int rt = 0; rt < 4; ++rt)
                #pragma unroll
                for (int ct = 0; ct < 2; ++ct)
                    acc[rt][ct] = __builtin_amdgcn_mfma_f32_16x16x32_bf16(
                        af[rt], bg[ct], acc[rt][ct], 0, 0, 0);
        }
    };

    STAGE(buf0, 0);
    __syncthreads();
    #pragma unroll 1
    for (int kc = 64; kc < KDIM - 64; kc += 128) {
        STAGE(buf1, kc);
        COMPUTE(buf0);
        __syncthreads();
        STAGE(buf0, kc + 64);
        COMPUTE(buf1);
        __syncthreads();
    }
    STAGE(buf1, KDIM - 64);
    COMPUTE(buf0);
    __syncthreads();
    COMPUTE(buf1);
    __syncthreads();   // all reads done before tile reuse below

    // Epilogue: store D2 + fused per-row min-key (round-0 scan).
    // C/D: col = lane&15, row = q*4+reg  [m89/m91-verified]
    unsigned long long* s_best = (unsigned long long*)tile;   // reuse post-barrier
    if (t < 64) s_best[t] = INVALID_KEY;
    __syncthreads();
    #pragma unroll
    for (int rt = 0; rt < 4; ++rt) {
        #pragma unroll
        for (int r = 0; r < 4; ++r) {
            int i = I0 + rt * 16 + q * 4 + r;
            unsigned long long kk = INVALID_KEY;
            #pragma unroll
            for (int ct = 0; ct < 2; ++ct) {
                int j = J0 + w * 32 + ct * 16 + m;
                float v = sq[i] + sq[j] - 2.0f * acc[rt][ct][r];
                v = (i == j) ? __builtin_inff() : fmaxf(v, 0.0f);
                D2[(size_t)i * NPTS + j] = v;
                if (i != j) {
                    unsigned long long key = mk_key(v, i, j);
                    kk = (key < kk) ? key : kk;
                }
            }
            #pragma unroll
            for (int mask = 1; mask < 16; mask <<= 1) {   // butterfly over m
                unsigned long long o = __shfl_xor(kk, mask);
                kk = (o < kk) ? o : kk;
            }
            if (m == 0) atomicMin(&s_best[rt * 16 + q * 4 + r], kk);
        }
    }
    __syncthreads();
    if (t < 64) atomicMin(&best0[I0 + t], s_best[t]);
}

// ---- Kernel 3: one Boruvka round, 256 blocks x 512 threads ---------------
// Merge micro-opts vs round-5: (1) vectorized state load (int4/ulonglong2);
// (2) pointer-jump barrier loop (5-6 x __syncthreads_or) replaced by 2
// compression sweeps (par[c]=par[par[c]], races benign: any read is an
// ancestor; non-roots are self-loops) + a barrier-free serial root walk
// (par is static after the hook phase; post-sweep depth ~ depth/4).
// Barriers/round ~13 -> ~9. Hook/rescan semantics unchanged.
__global__ __launch_bounds__(512) void boruvka_round(const float* __restrict__ D2,
                                                     const unsigned long long* __restrict__ bestP,
                                                     unsigned long long* __restrict__ bestN,
                                                     const int* __restrict__ compP,
                                                     int* __restrict__ compN,
                                                     float* __restrict__ ew,
                                                     int* __restrict__ ctl) {
    if (ctl[1]) return;   // MST complete
    __shared__ int sc[NPTS];                       // 8 KB
    __shared__ unsigned long long compBest[NPTS];  // 16 KB
    __shared__ int par[NPTS];                      // 8 KB, reused as rlist
    __shared__ int s_wsum[8];
    __shared__ int s_nroots;
    const int t = threadIdx.x;
    const int bid = blockIdx.x;
    const int lane = t & 63, w = t >> 6;           // w in 0..7

    if (t == 0) s_nroots = 0;
    const int4 cc = *(const int4*)(compP + t * 4);
    *(int4*)(sc + t * 4) = cc;
    const unsigned long long k0 = bestP[t * 4 + 0];
    const unsigned long long k1 = bestP[t * 4 + 1];
    const unsigned long long k2 = bestP[t * 4 + 2];
    const unsigned long long k3 = bestP[t * 4 + 3];
    compBest[t * 4 + 0] = INVALID_KEY;
    compBest[t * 4 + 1] = INVALID_KEY;
    compBest[t * 4 + 2] = INVALID_KEY;
    compBest[t * 4 + 3] = INVALID_KEY;
    __syncthreads();

    unsigned long long kreg[4] = {k0, k1, k2, k3};
    int oreg[4];
    #pragma unroll
    for (int e = 0; e < 4; ++e) {
        int v = t * 4 + e;
        unsigned long long k = kreg[e];
        int a = (int)((k >> 11) & 2047), b = (int)(k & 2047);
        oreg[e] = (a == v) ? b : a;
        if (k != INVALID_KEY && sc[oreg[e]] != sc[v])
            atomicMin(&compBest[sc[v]], k);
    }
    __syncthreads();

    // hook roots (smaller root survives mutual 2-cycle); block 0 records w
    #pragma unroll
    for (int e = 0; e < 4; ++e) {
        int c = t * 4 + e;
        int p = c;
        if (sc[c] == c) {
            unsigned long long k = compBest[c];
            if (k != INVALID_KEY) {
                int a = (int)((k >> 11) & 2047), b = (int)(k & 2047);
                int j = (sc[a] == c) ? b : a;
                int rj = sc[j];
                bool mutual = (compBest[rj] == k);  // keys unique per edge
                if (!(mutual && c < rj)) {
                    p = rj;
                    if (bid == 0)
                        ew[atomicAdd(&ctl[0], 1)] = __uint_as_float((unsigned)(k >> 22));
                }
            }
        }
        par[c] = p;
    }
    __syncthreads();                 // par complete; static from here on

    // 2 compression sweeps: par[c]=par[par[c]] (no-op for non-roots; write
    // races benign -- any value read is an ancestor of c's root)
    #pragma unroll
    for (int sw = 0; sw < 2; ++sw) {
        #pragma unroll
        for (int e = 0; e < 4; ++e) {
            int c = t * 4 + e;
            par[c] = par[par[c]];
        }
        __syncthreads();
    }

    // barrier-free serial root walk (par static, chains short post-sweep)
    int newsc[4]; int rc = 0;
    #pragma unroll
    for (int e = 0; e < 4; ++e) {
        int v = t * 4 + e;
        int r = sc[v];
        int p = par[r];
        while (p != r) { r = p; p = par[r]; }
        newsc[e] = r;
        if (r == v) rc++;
    }
    if (rc) atomicAdd(&s_nroots, rc);
    __syncthreads();                 // walks + nroots adds done; par reusable
    #pragma unroll
    for (int e = 0; e < 4; ++e) sc[t * 4 + e] = newsc[e];
    __syncthreads();                 // sc visible
    const int nroots = s_nroots;

    if (bid == 0) {
        *(int4*)(compN + t * 4) = make_int4(newsc[0], newsc[1], newsc[2], newsc[3]);
        if (t == 0 && nroots == 1) ctl[1] = 1;
    }
    if (nroots == 1) return;

    // rescan list = vertices whose cached edge became internal
    int flags[4], lc = 0;
    #pragma unroll
    for (int e = 0; e < 4; ++e) {
        int v = t * 4 + e;
        flags[e] = (kreg[e] == INVALID_KEY) || (sc[oreg[e]] == sc[v]);
        lc += flags[e];
    }
    int scn = lc;                    // wave inclusive scan
    #pragma unroll
    for (int d = 1; d < 64; d <<= 1) {
        int o = __shfl_up(scn, d);
        if (lane >= d) scn += o;
    }
    if (lane == 63) s_wsum[w] = scn;
    __syncthreads();
    int wbase = 0;
    for (int i = 0; i < w; ++i) wbase += s_wsum[i];
    const int cnt = s_wsum[0] + s_wsum[1] + s_wsum[2] + s_wsum[3] +
                    s_wsum[4] + s_wsum[5] + s_wsum[6] + s_wsum[7];
    int base = wbase + scn - lc;
    int* rlist = par;
    #pragma unroll
    for (int e = 0; e < 4; ++e)
        if (flags[e]) rlist[base++] = t * 4 + e;
    __syncthreads();

    // carry-over still-valid caches: block bid owns vertices [bid*8, bid*8+8)
    if (t < 8) {
        int v = bid * 8 + t;
        unsigned long long k = bestP[v];
        if (k != INVALID_KEY) {
            int a = (int)((k >> 11) & 2047), b = (int)(k & 2047);
            int o = (a == v) ? b : a;
            if (sc[o] != sc[v]) bestN[v] = k;
        }
    }
    // rescan: wave w handles rlist[bid*8 + w]
    int widx = bid * 8 + w;
    if (widx < cnt) {
        int v = rlist[widx];
        int mc = sc[v];
        const float* row = D2 + (size_t)v * NPTS;
        unsigned long long best = INVALID_KEY;
        #pragma unroll
        for (int k = 0; k < 8; ++k) {
            int j0 = k * 256 + lane * 4;
            float4 w4 = *(const float4*)(row + j0);
            int4 c4 = *(const int4*)(sc + j0);
            float wa[4] = {w4.x, w4.y, w4.z, w4.w};
            int ca[4] = {c4.x, c4.y, c4.z, c4.w};
            #pragma unroll
            for (int e = 0; e < 4; ++e) {
                if (ca[e] != mc) {
                    unsigned long long key = mk_key(wa[e], v, j0 + e);
                    best = (key < best) ? key : best;
                }
            }
        }
        for (int off = 32; off; off >>= 1) {
            unsigned long long o = __shfl_down(best, off);
            best = (o < best) ? o : best;
        }
        if (lane == 0) bestN[v] = best;
    }
}

// ---- Kernel 4: sort 2047 weights asc, sqrt, write out --------------------
__global__ __launch_bounds__(1024) void sort_out_kernel(const float* __restrict__ ew,
                                                        float* __restrict__ out) {
    __shared__ float wl[NPTS];
    const int t = threadIdx.x;
    for (int i = t; i < NPTS; i += 1024)
        wl[i] = (i < NPTS - 1) ? ew[i] : __builtin_inff();
    __syncthreads();
    for (int k = 2; k <= NPTS; k <<= 1) {
        for (int j = k >> 1; j > 0; j >>= 1) {
            for (int i = t; i < NPTS; i += 1024) {
                int l = i ^ j;
                if (l > i) {
                    float a = wl[i], b = wl[l];
                    bool up = ((i & k) == 0);
                    if ((a > b) == up) { wl[i] = b; wl[l] = a; }
                }
            }
            __syncthreads();
        }
    }
    for (int i = t; i < NPTS - 1; i += 1024)
        out[i] = sqrtf(fmaxf(wl[i], 0.0f));
}

extern "C" void kernel_launch(void* const* d_in, const int* in_sizes, int n_in,
                              void* d_out, int out_size, void* d_ws, size_t ws_size,
                              hipStream_t stream) {
    const float* x = (const float*)d_in[0];
    float* out = (float*)d_out;
    char* ws = (char*)d_ws;
    unsigned short* xb = (unsigned short*)ws;                          // 16 MB
    float* D2 = (float*)(ws + 16777216);                               // 16 MB
    size_t o = 33554432;
    float* sq = (float*)(ws + o);                  o += 8192;
    unsigned long long* best0 = (unsigned long long*)(ws + o); o += 16384;
    unsigned long long* best1 = (unsigned long long*)(ws + o); o += 16384;
    int* comp0 = (int*)(ws + o);                   o += 8192;
    int* comp1 = (int*)(ws + o);                   o += 8192;
    float* ew = (float*)(ws + o);                  o += 8192;
    int* ctl = (int*)(ws + o);

    hipLaunchKernelGGL(convert_sqnorm_kernel, dim3(NPTS), dim3(256), 0, stream,
                       x, xb, sq, comp0, best0, ctl);
    hipLaunchKernelGGL(gemm_d2_glds, dim3(512), dim3(256), 0, stream,
                       xb, sq, D2, best0);
    for (int r = 0; r < 11; ++r) {
        unsigned long long* bp = (r & 1) ? best1 : best0;
        unsigned long long* bn = (r & 1) ? best0 : best1;
        int* cp = (r & 1) ? comp1 : comp0;
        int* cn = (r & 1) ? comp0 : comp1;
        hipLaunchKernelGGL(boruvka_round, dim3(256), dim3(512), 0, stream,
                           D2, bp, bn, cp, cn, ew, ctl);
    }
    hipLaunchKernelGGL(sort_out_kernel, dim3(1), dim3(1024), 0, stream, ew, out);
}

// Round 10
// 199.810 us; speedup vs baseline: 1.0891x; 1.0027x over previous
//
#include <hip/hip_runtime.h>
#include <stdint.h>

#define NPTS 2048
#define KDIM 4096
#define INVALID_KEY 0xFFFFFFFFFFFFFFFFull

typedef __bf16 bf16x8 __attribute__((ext_vector_type(8)));
typedef float f32x4 __attribute__((ext_vector_type(4)));

__device__ __forceinline__ unsigned short f2bf(float f) {
    unsigned int u = __float_as_uint(f);
    u = (u + 0x7FFFu + ((u >> 16) & 1u)) >> 16;   // RNE
    return (unsigned short)u;
}

__device__ __forceinline__ void gld_lds16(const unsigned short* g, unsigned short* l) {
    __builtin_amdgcn_global_load_lds(
        (const __attribute__((address_space(1))) unsigned int*)g,
        (__attribute__((address_space(3))) unsigned int*)l, 16, 0, 0);
}

// key = (d2_bits << 22) | (min(i,j) << 11) | max(i,j): unique per undirected
// edge -> tie-free total order -> hooking cycles are only mutual 2-cycles.
__device__ __forceinline__ unsigned long long mk_key(float w, int i, int j) {
    unsigned long long a = (i < j) ? i : j;
    unsigned long long b = (i < j) ? j : i;
    return ((unsigned long long)__float_as_uint(w) << 22) | (a << 11) | b;
}

// ---- Kernel 1: fp32->bf16 convert + sqnorm + state init ------------------
__global__ __launch_bounds__(256) void convert_sqnorm_kernel(const float* __restrict__ x,
                                                             unsigned short* __restrict__ xb,
                                                             float* __restrict__ sq,
                                                             int* __restrict__ comp0,
                                                             unsigned long long* __restrict__ best0,
                                                             int* __restrict__ ctl) {
    const int row = blockIdx.x;
    const float* xr = x + (size_t)row * KDIM;
    unsigned short* xbr = xb + (size_t)row * KDIM;
    const int t = threadIdx.x;
    float s = 0.f;
    #pragma unroll
    for (int k = 0; k < 4; ++k) {
        int c = t * 4 + k * 1024;
        float4 v = *(const float4*)(xr + c);
        s += v.x * v.x + v.y * v.y + v.z * v.z + v.w * v.w;
        uint2 u;
        u.x = (unsigned)f2bf(v.x) | ((unsigned)f2bf(v.y) << 16);
        u.y = (unsigned)f2bf(v.z) | ((unsigned)f2bf(v.w) << 16);
        *(uint2*)(xbr + c) = u;
    }
    for (int off = 32; off; off >>= 1) s += __shfl_down(s, off);
    __shared__ float p[4];
    if ((t & 63) == 0) p[t >> 6] = s;
    __syncthreads();
    if (t == 0) {
        sq[row] = p[0] + p[1] + p[2] + p[3];
        comp0[row] = row;
        best0[row] = INVALID_KEY;
        if (row == 0) { ctl[0] = 0; ctl[1] = 0; }
    }
}

// ---- Kernel 2: GEMM D2, 64x128, BK=64, 2-phase dbuf + XCD swizzle --------
// FROZEN round-7 verified version (best sample 54.0 us, MfmaUtil ~24%).
// Counted-vmcnt pipeline abandoned permanently: crashed twice (r1 @72KB LDS,
// r9 @48KB LDS) -> mechanism, not allocation (m152: raw-barrier schedules
// race unless co-designed). Tile ladder measured: 64x64@4blk/CU=69us,
// 64x128@2blk/CU=54-66us, triangular 272-tile@1blk/CU=62us.
__global__ __launch_bounds__(256, 2) void gemm_d2_glds(const unsigned short* __restrict__ xb,
                                                       const float* __restrict__ sq,
                                                       float* __restrict__ D2,
                                                       unsigned long long* __restrict__ best0) {
    __shared__ __align__(16) unsigned short tile[2 * 12288];  // 48 KB, 2 bufs
    const int swz = (blockIdx.x & 7) * 64 + (blockIdx.x >> 3);  // XCD-chunked
    const int I0 = (swz >> 4) * 64;    // by = swz/16
    const int J0 = (swz & 15) * 128;   // bx = swz%16
    const int t = threadIdx.x;
    const int lane = t & 63;
    const int w = t >> 6;
    const int m = lane & 15, q = lane >> 4;

    // Staging lane l holds (row=l>>2, seg=(l&3)^((l>>3)&3)) within a chunk;
    // reader granule (m, q) sits at 32*m + 8*(q^((m>>1)&3)) elems -> 2-way
    // bank aliasing only (free). Swizzle applied on BOTH sides (rule #21).
    const int rp = lane >> 2;
    const int sg = (lane & 3) ^ ((lane >> 3) & 3);
    const unsigned short* gsrc[6]; int ldoff[6];
    #pragma unroll
    for (int s = 0; s < 2; ++s)
        #pragma unroll
        for (int ci = 0; ci < 3; ++ci) {
            int c = w * 3 + ci;                       // chunk 0..11 within sub-tile
            int rowbase = (c < 4) ? (I0 + c * 16) : (J0 + (c - 4) * 16);
            int idx = s * 3 + ci;
            gsrc[idx] = xb + (size_t)(rowbase + rp) * KDIM + s * 32 + sg * 8;
            ldoff[idx] = (s * 12 + c) * 512;          // wave-uniform LDS chunk base
        }
    const int fro = m * 32 + ((q ^ ((m >> 1) & 3)) * 8);

    f32x4 acc[4][2] = {};
    unsigned short* buf0 = tile;
    unsigned short* buf1 = tile + 12288;

    auto STAGE = [&](unsigned short* base, int kc) {
        #pragma unroll
        for (int idx = 0; idx < 6; ++idx)
            gld_lds16(gsrc[idx] + kc, base + ldoff[idx]);
    };
    auto COMPUTE = [&](const unsigned short* base) {
        #pragma unroll
        for (int s = 0; s < 2; ++s) {
            bf16x8 af[4], bg[2];
            #pragma unroll
            for (int rt = 0; rt < 4; ++rt)
                af[rt] = *(const bf16x8*)(base + (s * 12 + rt) * 512 + fro);
            #pragma unroll
            for (int ct = 0; ct < 2; ++ct)
                bg[ct] = *(const bf16x8*)(base + (s * 12 + 4 + w * 2 + ct) * 512 + fro);
            #pragma unroll
            for (int rt = 0; rt < 4; ++rt)
                #pragma unroll
                for (int ct = 0; ct < 2; ++ct)
                    acc[rt][ct] = __builtin_amdgcn_mfma_f32_16x16x32_bf16(
                        af[rt], bg[ct], acc[rt][ct], 0, 0, 0);
        }
    };

    STAGE(buf0, 0);
    __syncthreads();
    #pragma unroll 1
    for (int kc = 64; kc < KDIM - 64; kc += 128) {
        STAGE(buf1, kc);
        COMPUTE(buf0);
        __syncthreads();
        STAGE(buf0, kc + 64);
        COMPUTE(buf1);
        __syncthreads();
    }
    STAGE(buf1, KDIM - 64);
    COMPUTE(buf0);
    __syncthreads();
    COMPUTE(buf1);
    __syncthreads();   // all reads done before tile reuse below

    // Epilogue: store D2 + fused per-row min-key (round-0 scan).
    // C/D: col = lane&15, row = q*4+reg  [m89/m91-verified]
    unsigned long long* s_best = (unsigned long long*)tile;   // reuse post-barrier
    if (t < 64) s_best[t] = INVALID_KEY;
    __syncthreads();
    #pragma unroll
    for (int rt = 0; rt < 4; ++rt) {
        #pragma unroll
        for (int r = 0; r < 4; ++r) {
            int i = I0 + rt * 16 + q * 4 + r;
            unsigned long long kk = INVALID_KEY;
            #pragma unroll
            for (int ct = 0; ct < 2; ++ct) {
                int j = J0 + w * 32 + ct * 16 + m;
                float v = sq[i] + sq[j] - 2.0f * acc[rt][ct][r];
                v = (i == j) ? __builtin_inff() : fmaxf(v, 0.0f);
                D2[(size_t)i * NPTS + j] = v;
                if (i != j) {
                    unsigned long long key = mk_key(v, i, j);
                    kk = (key < kk) ? key : kk;
                }
            }
            #pragma unroll
            for (int mask = 1; mask < 16; mask <<= 1) {   // butterfly over m
                unsigned long long o = __shfl_xor(kk, mask);
                kk = (o < kk) ? o : kk;
            }
            if (m == 0) atomicMin(&s_best[rt * 16 + q * 4 + r], kk);
        }
    }
    __syncthreads();
    if (t < 64) atomicMin(&best0[I0 + t], s_best[t]);
}

// ---- Kernel 3: one Boruvka round, 256 blocks x 1024 threads --------------
// vs round-8's 512-thread version: per-thread serial work halves (2 verts/
// thread) across every phase of the per-block critical path (load, atomicMin,
// hook, sweeps, walk, scan). Same algorithm, mechanical 4->2 re-indexing.
// Grid stays 256: carry-over ownership bid*8 unchanged; rescan slots
// bid*16+w (4096 >= cnt). ~9 barriers/round as before.
__global__ __launch_bounds__(1024) void boruvka_round(const float* __restrict__ D2,
                                                      const unsigned long long* __restrict__ bestP,
                                                      unsigned long long* __restrict__ bestN,
                                                      const int* __restrict__ compP,
                                                      int* __restrict__ compN,
                                                      float* __restrict__ ew,
                                                      int* __restrict__ ctl) {
    if (ctl[1]) return;   // MST complete
    __shared__ int sc[NPTS];                       // 8 KB
    __shared__ unsigned long long compBest[NPTS];  // 16 KB
    __shared__ int par[NPTS];                      // 8 KB, reused as rlist
    __shared__ int s_wsum[16];
    __shared__ int s_nroots;
    const int t = threadIdx.x;                     // 0..1023
    const int bid = blockIdx.x;
    const int lane = t & 63, w = t >> 6;           // w in 0..15

    if (t == 0) s_nroots = 0;
    const int2 cc = *(const int2*)(compP + t * 2);
    sc[t * 2 + 0] = cc.x;
    sc[t * 2 + 1] = cc.y;
    const unsigned long long k0 = bestP[t * 2 + 0];
    const unsigned long long k1 = bestP[t * 2 + 1];
    compBest[t * 2 + 0] = INVALID_KEY;
    compBest[t * 2 + 1] = INVALID_KEY;
    __syncthreads();

    unsigned long long kreg[2] = {k0, k1};
    int oreg[2];
    #pragma unroll
    for (int e = 0; e < 2; ++e) {
        int v = t * 2 + e;
        unsigned long long k = kreg[e];
        int a = (int)((k >> 11) & 2047), b = (int)(k & 2047);
        oreg[e] = (a == v) ? b : a;
        if (k != INVALID_KEY && sc[oreg[e]] != sc[v])
            atomicMin(&compBest[sc[v]], k);
    }
    __syncthreads();

    // hook roots (smaller root survives mutual 2-cycle); block 0 records w
    #pragma unroll
    for (int e = 0; e < 2; ++e) {
        int c = t * 2 + e;
        int p = c;
        if (sc[c] == c) {
            unsigned long long k = compBest[c];
            if (k != INVALID_KEY) {
                int a = (int)((k >> 11) & 2047), b = (int)(k & 2047);
                int j = (sc[a] == c) ? b : a;
                int rj = sc[j];
                bool mutual = (compBest[rj] == k);  // keys unique per edge
                if (!(mutual && c < rj)) {
                    p = rj;
                    if (bid == 0)
                        ew[atomicAdd(&ctl[0], 1)] = __uint_as_float((unsigned)(k >> 22));
                }
            }
        }
        par[c] = p;
    }
    __syncthreads();                 // par complete; static from here on

    // 2 compression sweeps: par[c]=par[par[c]] (no-op for non-roots; write
    // races benign -- any value read is an ancestor of c's root)
    #pragma unroll
    for (int sw = 0; sw < 2; ++sw) {
        #pragma unroll
        for (int e = 0; e < 2; ++e) {
            int c = t * 2 + e;
            par[c] = par[par[c]];
        }
        __syncthreads();
    }

    // barrier-free serial root walk (par static, chains short post-sweep)
    int newsc[2]; int rc = 0;
    #pragma unroll
    for (int e = 0; e < 2; ++e) {
        int v = t * 2 + e;
        int r = sc[v];
        int p = par[r];
        while (p != r) { r = p; p = par[r]; }
        newsc[e] = r;
        if (r == v) rc++;
    }
    if (rc) atomicAdd(&s_nroots, rc);
    __syncthreads();                 // walks + nroots adds done; par reusable
    sc[t * 2 + 0] = newsc[0];
    sc[t * 2 + 1] = newsc[1];
    __syncthreads();                 // sc visible
    const int nroots = s_nroots;

    if (bid == 0) {
        *(int2*)(compN + t * 2) = make_int2(newsc[0], newsc[1]);
        if (t == 0 && nroots == 1) ctl[1] = 1;
    }
    if (nroots == 1) return;

    // rescan list = vertices whose cached edge became internal
    int flags[2], lc = 0;
    #pragma unroll
    for (int e = 0; e < 2; ++e) {
        int v = t * 2 + e;
        flags[e] = (kreg[e] == INVALID_KEY) || (sc[oreg[e]] == sc[v]);
        lc += flags[e];
    }
    int scn = lc;                    // wave inclusive scan
    #pragma unroll
    for (int d = 1; d < 64; d <<= 1) {
        int o = __shfl_up(scn, d);
        if (lane >= d) scn += o;
    }
    if (lane == 63) s_wsum[w] = scn;
    __syncthreads();
    int wbase = 0;
    for (int i = 0; i < w; ++i) wbase += s_wsum[i];
    int cnt = 0;
    #pragma unroll
    for (int i = 0; i < 16; ++i) cnt += s_wsum[i];
    int base = wbase + scn - lc;
    int* rlist = par;
    #pragma unroll
    for (int e = 0; e < 2; ++e)
        if (flags[e]) rlist[base++] = t * 2 + e;
    __syncthreads();

    // carry-over still-valid caches: block bid owns vertices [bid*8, bid*8+8)
    if (t < 8) {
        int v = bid * 8 + t;
        unsigned long long k = bestP[v];
        if (k != INVALID_KEY) {
            int a = (int)((k >> 11) & 2047), b = (int)(k & 2047);
            int o = (a == v) ? b : a;
            if (sc[o] != sc[v]) bestN[v] = k;
        }
    }
    // rescan: wave w handles rlist[bid*16 + w] (4096 slots cover cnt<=2048)
    int widx = bid * 16 + w;
    if (widx < cnt) {
        int v = rlist[widx];
        int mc = sc[v];
        const float* row = D2 + (size_t)v * NPTS;
        unsigned long long best = INVALID_KEY;
        #pragma unroll
        for (int k = 0; k < 8; ++k) {
            int j0 = k * 256 + lane * 4;
            float4 w4 = *(const float4*)(row + j0);
            int4 c4 = *(const int4*)(sc + j0);
            float wa[4] = {w4.x, w4.y, w4.z, w4.w};
            int ca[4] = {c4.x, c4.y, c4.z, c4.w};
            #pragma unroll
            for (int e = 0; e < 4; ++e) {
                if (ca[e] != mc) {
                    unsigned long long key = mk_key(wa[e], v, j0 + e);
                    best = (key < best) ? key : best;
                }
            }
        }
        for (int off = 32; off; off >>= 1) {
            unsigned long long o = __shfl_down(best, off);
            best = (o < best) ? o : best;
        }
        if (lane == 0) bestN[v] = best;
    }
}

// ---- Kernel 4: sort 2047 weights asc, sqrt, write out --------------------
__global__ __launch_bounds__(1024) void sort_out_kernel(const float* __restrict__ ew,
                                                        float* __restrict__ out) {
    __shared__ float wl[NPTS];
    const int t = threadIdx.x;
    for (int i = t; i < NPTS; i += 1024)
        wl[i] = (i < NPTS - 1) ? ew[i] : __builtin_inff();
    __syncthreads();
    for (int k = 2; k <= NPTS; k <<= 1) {
        for (int j = k >> 1; j > 0; j >>= 1) {
            for (int i = t; i < NPTS; i += 1024) {
                int l = i ^ j;
                if (l > i) {
                    float a = wl[i], b = wl[l];
                    bool up = ((i & k) == 0);
                    if ((a > b) == up) { wl[i] = b; wl[l] = a; }
                }
            }
            __syncthreads();
        }
    }
    for (int i = t; i < NPTS - 1; i += 1024)
        out[i] = sqrtf(fmaxf(wl[i], 0.0f));
}

extern "C" void kernel_launch(void* const* d_in, const int* in_sizes, int n_in,
                              void* d_out, int out_size, void* d_ws, size_t ws_size,
                              hipStream_t stream) {
    const float* x = (const float*)d_in[0];
    float* out = (float*)d_out;
    char* ws = (char*)d_ws;
    unsigned short* xb = (unsigned short*)ws;                          // 16 MB
    float* D2 = (float*)(ws + 16777216);                               // 16 MB
    size_t o = 33554432;
    float* sq = (float*)(ws + o);                  o += 8192;
    unsigned long long* best0 = (unsigned long long*)(ws + o); o += 16384;
    unsigned long long* best1 = (unsigned long long*)(ws + o); o += 16384;
    int* comp0 = (int*)(ws + o);                   o += 8192;
    int* comp1 = (int*)(ws + o);                   o += 8192;
    float* ew = (float*)(ws + o);                  o += 8192;
    int* ctl = (int*)(ws + o);

    hipLaunchKernelGGL(convert_sqnorm_kernel, dim3(NPTS), dim3(256), 0, stream,
                       x, xb, sq, comp0, best0, ctl);
    hipLaunchKernelGGL(gemm_d2_glds, dim3(512), dim3(256), 0, stream,
                       xb, sq, D2, best0);
    for (int r = 0; r < 11; ++r) {
        unsigned long long* bp = (r & 1) ? best1 : best0;
        unsigned long long* bn = (r & 1) ? best0 : best1;
        int* cp = (r & 1) ? comp1 : comp0;
        int* cn = (r & 1) ? comp0 : comp1;
        hipLaunchKernelGGL(boruvka_round, dim3(256), dim3(1024), 0, stream,
                           D2, bp, bn, cp, cn, ew, ctl);
    }
    hipLaunchKernelGGL(sort_out_kernel, dim3(1), dim3(1024), 0, stream, ew, out);
}

// Round 11
// 188.340 us; speedup vs baseline: 1.1555x; 1.0609x over previous
//
#include <hip/hip_runtime.h>
#include <stdint.h>

#define NPTS 2048
#define KDIM 4096
#define INVALID_KEY 0xFFFFFFFFFFFFFFFFull

typedef __bf16 bf16x8 __attribute__((ext_vector_type(8)));
typedef float f32x4 __attribute__((ext_vector_type(4)));

__device__ __forceinline__ unsigned short f2bf(float f) {
    unsigned int u = __float_as_uint(f);
    u = (u + 0x7FFFu + ((u >> 16) & 1u)) >> 16;   // RNE
    return (unsigned short)u;
}

__device__ __forceinline__ void gld_lds16(const unsigned short* g, unsigned short* l) {
    __builtin_amdgcn_global_load_lds(
        (const __attribute__((address_space(1))) unsigned int*)g,
        (__attribute__((address_space(3))) unsigned int*)l, 16, 0, 0);
}

// key = (d2_bits << 22) | (min(i,j) << 11) | max(i,j): unique per undirected
// edge -> tie-free total order -> hooking cycles are only mutual 2-cycles.
__device__ __forceinline__ unsigned long long mk_key(float w, int i, int j) {
    unsigned long long a = (i < j) ? i : j;
    unsigned long long b = (i < j) ? j : i;
    return ((unsigned long long)__float_as_uint(w) << 22) | (a << 11) | b;
}

// ---- Kernel 1: fp32->bf16 convert + sqnorm + state init ------------------
__global__ __launch_bounds__(256) void convert_sqnorm_kernel(const float* __restrict__ x,
                                                             unsigned short* __restrict__ xb,
                                                             float* __restrict__ sq,
                                                             int* __restrict__ comp0,
                                                             unsigned long long* __restrict__ best0,
                                                             int* __restrict__ ctl) {
    const int row = blockIdx.x;
    const float* xr = x + (size_t)row * KDIM;
    unsigned short* xbr = xb + (size_t)row * KDIM;
    const int t = threadIdx.x;
    float s = 0.f;
    #pragma unroll
    for (int k = 0; k < 4; ++k) {
        int c = t * 4 + k * 1024;
        float4 v = *(const float4*)(xr + c);
        s += v.x * v.x + v.y * v.y + v.z * v.z + v.w * v.w;
        uint2 u;
        u.x = (unsigned)f2bf(v.x) | ((unsigned)f2bf(v.y) << 16);
        u.y = (unsigned)f2bf(v.z) | ((unsigned)f2bf(v.w) << 16);
        *(uint2*)(xbr + c) = u;
    }
    for (int off = 32; off; off >>= 1) s += __shfl_down(s, off);
    __shared__ float p[4];
    if ((t & 63) == 0) p[t >> 6] = s;
    __syncthreads();
    if (t == 0) {
        sq[row] = p[0] + p[1] + p[2] + p[3];
        comp0[row] = row;
        best0[row] = INVALID_KEY;
        if (row == 0) { ctl[0] = 0; ctl[1] = 0; }
    }
}

// ---- Kernel 2: GEMM D2, 64x128, BK=64, 2-phase dbuf + XCD swizzle --------
// FROZEN round-7 verified version (54.0 us reproduced, MfmaUtil ~24%).
// Counted-vmcnt abandoned (crashed at 72KB AND 48KB LDS -> mechanism).
// Tile/occupancy ladder fully measured; this is the structure's plateau.
__global__ __launch_bounds__(256, 2) void gemm_d2_glds(const unsigned short* __restrict__ xb,
                                                       const float* __restrict__ sq,
                                                       float* __restrict__ D2,
                                                       unsigned long long* __restrict__ best0) {
    __shared__ __align__(16) unsigned short tile[2 * 12288];  // 48 KB, 2 bufs
    const int swz = (blockIdx.x & 7) * 64 + (blockIdx.x >> 3);  // XCD-chunked
    const int I0 = (swz >> 4) * 64;    // by = swz/16
    const int J0 = (swz & 15) * 128;   // bx = swz%16
    const int t = threadIdx.x;
    const int lane = t & 63;
    const int w = t >> 6;
    const int m = lane & 15, q = lane >> 4;

    // Staging lane l holds (row=l>>2, seg=(l&3)^((l>>3)&3)) within a chunk;
    // reader granule (m, q) sits at 32*m + 8*(q^((m>>1)&3)) elems -> 2-way
    // bank aliasing only (free). Swizzle applied on BOTH sides (rule #21).
    const int rp = lane >> 2;
    const int sg = (lane & 3) ^ ((lane >> 3) & 3);
    const unsigned short* gsrc[6]; int ldoff[6];
    #pragma unroll
    for (int s = 0; s < 2; ++s)
        #pragma unroll
        for (int ci = 0; ci < 3; ++ci) {
            int c = w * 3 + ci;                       // chunk 0..11 within sub-tile
            int rowbase = (c < 4) ? (I0 + c * 16) : (J0 + (c - 4) * 16);
            int idx = s * 3 + ci;
            gsrc[idx] = xb + (size_t)(rowbase + rp) * KDIM + s * 32 + sg * 8;
            ldoff[idx] = (s * 12 + c) * 512;          // wave-uniform LDS chunk base
        }
    const int fro = m * 32 + ((q ^ ((m >> 1) & 3)) * 8);

    f32x4 acc[4][2] = {};
    unsigned short* buf0 = tile;
    unsigned short* buf1 = tile + 12288;

    auto STAGE = [&](unsigned short* base, int kc) {
        #pragma unroll
        for (int idx = 0; idx < 6; ++idx)
            gld_lds16(gsrc[idx] + kc, base + ldoff[idx]);
    };
    auto COMPUTE = [&](const unsigned short* base) {
        #pragma unroll
        for (int s = 0; s < 2; ++s) {
            bf16x8 af[4], bg[2];
            #pragma unroll
            for (int rt = 0; rt < 4; ++rt)
                af[rt] = *(const bf16x8*)(base + (s * 12 + rt) * 512 + fro);
            #pragma unroll
            for (int ct = 0; ct < 2; ++ct)
                bg[ct] = *(const bf16x8*)(base + (s * 12 + 4 + w * 2 + ct) * 512 + fro);
            #pragma unroll
            for (int rt = 0; rt < 4; ++rt)
                #pragma unroll
                for (int ct = 0; ct < 2; ++ct)
                    acc[rt][ct] = __builtin_amdgcn_mfma_f32_16x16x32_bf16(
                        af[rt], bg[ct], acc[rt][ct], 0, 0, 0);
        }
    };

    STAGE(buf0, 0);
    __syncthreads();
    #pragma unroll 1
    for (int kc = 64; kc < KDIM - 64; kc += 128) {
        STAGE(buf1, kc);
        COMPUTE(buf0);
        __syncthreads();
        STAGE(buf0, kc + 64);
        COMPUTE(buf1);
        __syncthreads();
    }
    STAGE(buf1, KDIM - 64);
    COMPUTE(buf0);
    __syncthreads();
    COMPUTE(buf1);
    __syncthreads();   // all reads done before tile reuse below

    // Epilogue: store D2 + fused per-row min-key (round-0 scan).
    // C/D: col = lane&15, row = q*4+reg  [m89/m91-verified]
    unsigned long long* s_best = (unsigned long long*)tile;   // reuse post-barrier
    if (t < 64) s_best[t] = INVALID_KEY;
    __syncthreads();
    #pragma unroll
    for (int rt = 0; rt < 4; ++rt) {
        #pragma unroll
        for (int r = 0; r < 4; ++r) {
            int i = I0 + rt * 16 + q * 4 + r;
            unsigned long long kk = INVALID_KEY;
            #pragma unroll
            for (int ct = 0; ct < 2; ++ct) {
                int j = J0 + w * 32 + ct * 16 + m;
                float v = sq[i] + sq[j] - 2.0f * acc[rt][ct][r];
                v = (i == j) ? __builtin_inff() : fmaxf(v, 0.0f);
                D2[(size_t)i * NPTS + j] = v;
                if (i != j) {
                    unsigned long long key = mk_key(v, i, j);
                    kk = (key < kk) ? key : kk;
                }
            }
            #pragma unroll
            for (int mask = 1; mask < 16; mask <<= 1) {   // butterfly over m
                unsigned long long o = __shfl_xor(kk, mask);
                kk = (o < kk) ? o : kk;
            }
            if (m == 0) atomicMin(&s_best[rt * 16 + q * 4 + r], kk);
        }
    }
    __syncthreads();
    if (t < 64) atomicMin(&best0[I0 + t], s_best[t]);
}

// ---- Kernel 3: one Boruvka round, 256 blocks x 1024 threads --------------
// (FROZEN round-10 version; chain is launch/latency-bound -- 512->1024
// thread reshape was neutral, so per-round floor is structural.)
__global__ __launch_bounds__(1024) void boruvka_round(const float* __restrict__ D2,
                                                      const unsigned long long* __restrict__ bestP,
                                                      unsigned long long* __restrict__ bestN,
                                                      const int* __restrict__ compP,
                                                      int* __restrict__ compN,
                                                      float* __restrict__ ew,
                                                      int* __restrict__ ctl) {
    if (ctl[1]) return;   // MST complete
    __shared__ int sc[NPTS];                       // 8 KB
    __shared__ unsigned long long compBest[NPTS];  // 16 KB
    __shared__ int par[NPTS];                      // 8 KB, reused as rlist
    __shared__ int s_wsum[16];
    __shared__ int s_nroots;
    const int t = threadIdx.x;                     // 0..1023
    const int bid = blockIdx.x;
    const int lane = t & 63, w = t >> 6;           // w in 0..15

    if (t == 0) s_nroots = 0;
    const int2 cc = *(const int2*)(compP + t * 2);
    sc[t * 2 + 0] = cc.x;
    sc[t * 2 + 1] = cc.y;
    const unsigned long long k0 = bestP[t * 2 + 0];
    const unsigned long long k1 = bestP[t * 2 + 1];
    compBest[t * 2 + 0] = INVALID_KEY;
    compBest[t * 2 + 1] = INVALID_KEY;
    __syncthreads();

    unsigned long long kreg[2] = {k0, k1};
    int oreg[2];
    #pragma unroll
    for (int e = 0; e < 2; ++e) {
        int v = t * 2 + e;
        unsigned long long k = kreg[e];
        int a = (int)((k >> 11) & 2047), b = (int)(k & 2047);
        oreg[e] = (a == v) ? b : a;
        if (k != INVALID_KEY && sc[oreg[e]] != sc[v])
            atomicMin(&compBest[sc[v]], k);
    }
    __syncthreads();

    // hook roots (smaller root survives mutual 2-cycle); block 0 records w
    #pragma unroll
    for (int e = 0; e < 2; ++e) {
        int c = t * 2 + e;
        int p = c;
        if (sc[c] == c) {
            unsigned long long k = compBest[c];
            if (k != INVALID_KEY) {
                int a = (int)((k >> 11) & 2047), b = (int)(k & 2047);
                int j = (sc[a] == c) ? b : a;
                int rj = sc[j];
                bool mutual = (compBest[rj] == k);  // keys unique per edge
                if (!(mutual && c < rj)) {
                    p = rj;
                    if (bid == 0)
                        ew[atomicAdd(&ctl[0], 1)] = __uint_as_float((unsigned)(k >> 22));
                }
            }
        }
        par[c] = p;
    }
    __syncthreads();                 // par complete; static from here on

    // 2 compression sweeps: par[c]=par[par[c]] (no-op for non-roots; write
    // races benign -- any value read is an ancestor of c's root)
    #pragma unroll
    for (int sw = 0; sw < 2; ++sw) {
        #pragma unroll
        for (int e = 0; e < 2; ++e) {
            int c = t * 2 + e;
            par[c] = par[par[c]];
        }
        __syncthreads();
    }

    // barrier-free serial root walk (par static, chains short post-sweep)
    int newsc[2]; int rc = 0;
    #pragma unroll
    for (int e = 0; e < 2; ++e) {
        int v = t * 2 + e;
        int r = sc[v];
        int p = par[r];
        while (p != r) { r = p; p = par[r]; }
        newsc[e] = r;
        if (r == v) rc++;
    }
    if (rc) atomicAdd(&s_nroots, rc);
    __syncthreads();                 // walks + nroots adds done; par reusable
    sc[t * 2 + 0] = newsc[0];
    sc[t * 2 + 1] = newsc[1];
    __syncthreads();                 // sc visible
    const int nroots = s_nroots;

    if (bid == 0) {
        *(int2*)(compN + t * 2) = make_int2(newsc[0], newsc[1]);
        if (t == 0 && nroots == 1) ctl[1] = 1;
    }
    if (nroots == 1) return;

    // rescan list = vertices whose cached edge became internal
    int flags[2], lc = 0;
    #pragma unroll
    for (int e = 0; e < 2; ++e) {
        int v = t * 2 + e;
        flags[e] = (kreg[e] == INVALID_KEY) || (sc[oreg[e]] == sc[v]);
        lc += flags[e];
    }
    int scn = lc;                    // wave inclusive scan
    #pragma unroll
    for (int d = 1; d < 64; d <<= 1) {
        int o = __shfl_up(scn, d);
        if (lane >= d) scn += o;
    }
    if (lane == 63) s_wsum[w] = scn;
    __syncthreads();
    int wbase = 0;
    for (int i = 0; i < w; ++i) wbase += s_wsum[i];
    int cnt = 0;
    #pragma unroll
    for (int i = 0; i < 16; ++i) cnt += s_wsum[i];
    int base = wbase + scn - lc;
    int* rlist = par;
    #pragma unroll
    for (int e = 0; e < 2; ++e)
        if (flags[e]) rlist[base++] = t * 2 + e;
    __syncthreads();

    // carry-over still-valid caches: block bid owns vertices [bid*8, bid*8+8)
    if (t < 8) {
        int v = bid * 8 + t;
        unsigned long long k = bestP[v];
        if (k != INVALID_KEY) {
            int a = (int)((k >> 11) & 2047), b = (int)(k & 2047);
            int o = (a == v) ? b : a;
            if (sc[o] != sc[v]) bestN[v] = k;
        }
    }
    // rescan: wave w handles rlist[bid*16 + w] (4096 slots cover cnt<=2048)
    int widx = bid * 16 + w;
    if (widx < cnt) {
        int v = rlist[widx];
        int mc = sc[v];
        const float* row = D2 + (size_t)v * NPTS;
        unsigned long long best = INVALID_KEY;
        #pragma unroll
        for (int k = 0; k < 8; ++k) {
            int j0 = k * 256 + lane * 4;
            float4 w4 = *(const float4*)(row + j0);
            int4 c4 = *(const int4*)(sc + j0);
            float wa[4] = {w4.x, w4.y, w4.z, w4.w};
            int ca[4] = {c4.x, c4.y, c4.z, c4.w};
            #pragma unroll
            for (int e = 0; e < 4; ++e) {
                if (ca[e] != mc) {
                    unsigned long long key = mk_key(wa[e], v, j0 + e);
                    best = (key < best) ? key : best;
                }
            }
        }
        for (int off = 32; off; off >>= 1) {
            unsigned long long o = __shfl_down(best, off);
            best = (o < best) ? o : best;
        }
        if (lane == 0) bestN[v] = best;
    }
}

// ---- Kernel 4: sort 2047 weights asc, register-bitonic, sqrt, write ------
// vs the 66-barrier LDS bitonic (~13 us): thread t holds ranks {t, t+1024}
// in registers. j=1024 phase is within-thread (0 sync); j in [64,512] = 14
// phases via LDS (2 barriers each); j<=32 = 51 phases via __shfl_xor within
// the 64-lane wave (0 barriers). Barriers 66 -> 28. Compare-exchange rule
// (canonical): element at index i keeps (lower==up) ? min : max, where
// lower = (i&j)==0, up = (i&k)==0 -- identical semantics to the LDS version.
__global__ __launch_bounds__(1024) void sort_out_kernel(const float* __restrict__ ew,
                                                        float* __restrict__ out) {
    __shared__ float sh[NPTS];
    const int t = threadIdx.x;
    const int lane = t & 63;
    float v0 = ew[t];                                        // rank slot t (<2047)
    float v1 = (t + 1024 < NPTS - 1) ? ew[t + 1024] : __builtin_inff();

    #pragma unroll 1
    for (int k = 2; k <= NPTS; k <<= 1) {
        #pragma unroll 1
        for (int j = k >> 1; j > 0; j >>= 1) {
            if (j == 1024) {
                // partner within thread: i=t is lower, up=((t&2048)==0)=true
                float mn = fminf(v0, v1), mx = fmaxf(v0, v1);
                v0 = mn; v1 = mx;
            } else if (j >= 64) {
                sh[t] = v0; sh[t + 1024] = v1;
                __syncthreads();
                float o0 = sh[t ^ j];
                float o1 = sh[(t + 1024) ^ j];
                bool lo = ((t & j) == 0);                 // same for i and i+1024 (j<1024)
                bool up0 = ((t & k) == 0);
                bool up1 = (((t + 1024) & k) == 0);
                v0 = (lo == up0) ? fminf(v0, o0) : fmaxf(v0, o0);
                v1 = (lo == up1) ? fminf(v1, o1) : fmaxf(v1, o1);
                __syncthreads();                          // WAR before next write
            } else {
                float o0 = __shfl_xor(v0, j);
                float o1 = __shfl_xor(v1, j);
                bool lo = ((lane & j) == 0);              // j<64: t&j == lane&j
                bool up0 = ((t & k) == 0);
                bool up1 = (((t + 1024) & k) == 0);
                v0 = (lo == up0) ? fminf(v0, o0) : fmaxf(v0, o0);
                v1 = (lo == up1) ? fminf(v1, o1) : fmaxf(v1, o1);
            }
        }
    }
    out[t] = sqrtf(fmaxf(v0, 0.0f));                      // ranks 0..1023
    if (t + 1024 < NPTS - 1)
        out[t + 1024] = sqrtf(fmaxf(v1, 0.0f));           // ranks 1024..2046
}

extern "C" void kernel_launch(void* const* d_in, const int* in_sizes, int n_in,
                              void* d_out, int out_size, void* d_ws, size_t ws_size,
                              hipStream_t stream) {
    const float* x = (const float*)d_in[0];
    float* out = (float*)d_out;
    char* ws = (char*)d_ws;
    unsigned short* xb = (unsigned short*)ws;                          // 16 MB
    float* D2 = (float*)(ws + 16777216);                               // 16 MB
    size_t o = 33554432;
    float* sq = (float*)(ws + o);                  o += 8192;
    unsigned long long* best0 = (unsigned long long*)(ws + o); o += 16384;
    unsigned long long* best1 = (unsigned long long*)(ws + o); o += 16384;
    int* comp0 = (int*)(ws + o);                   o += 8192;
    int* comp1 = (int*)(ws + o);                   o += 8192;
    float* ew = (float*)(ws + o);                  o += 8192;
    int* ctl = (int*)(ws + o);

    hipLaunchKernelGGL(convert_sqnorm_kernel, dim3(NPTS), dim3(256), 0, stream,
                       x, xb, sq, comp0, best0, ctl);
    hipLaunchKernelGGL(gemm_d2_glds, dim3(512), dim3(256), 0, stream,
                       xb, sq, D2, best0);
    for (int r = 0; r < 11; ++r) {
        unsigned long long* bp = (r & 1) ? best1 : best0;
        unsigned long long* bn = (r & 1) ? best0 : best1;
        int* cp = (r & 1) ? comp1 : comp0;
        int* cn = (r & 1) ? comp0 : comp1;
        hipLaunchKernelGGL(boruvka_round, dim3(256), dim3(1024), 0, stream,
                           D2, bp, bn, cp, cn, ew, ctl);
    }
    hipLaunchKernelGGL(sort_out_kernel, dim3(1), dim3(1024), 0, stream, ew, out);
}